// Round 5
// baseline (495.019 us; speedup 1.0000x reference)
//
#include <hip/hip_runtime.h>

// argmin_c ||x-c|| == argmin_c (||c||^2 - 2 x.c). Cross-term via 3 f16 MFMA
// GEMMs (exact hi/lo split of fp32, lo*lo dropped ~2^-22 rel).
// Round 5: fix round-4 stride bug — preconverted rows are f16, so row stride
// is KK*2/16 = 96 uint4, not 192 (fp32 stride). Fast path otherwise unchanged;
// runtime fallback to the proven round-3 kernel if ws_size is too small.
typedef __fp16 f16x2 __attribute__((ext_vector_type(2)));
typedef __fp16 f16x8 __attribute__((ext_vector_type(8)));
typedef float f32x4 __attribute__((ext_vector_type(4)));

constexpr int MM = 32768;   // B*T tokens
constexpr int NN = 2048;    // clusters
constexpr int KK = 768;     // dim
constexpr int BM = 128;     // tokens per block
constexpr int BN = 128;     // clusters per block
constexpr int BK = 32;      // k-tile
constexpr int RSTR = KK * 2 / 16;   // = 96 uint4 per f16 row

// Fast-path workspace layout (bytes)
constexpr size_t WS_AH   = 0;
constexpr size_t WS_AL   = WS_AH + (size_t)MM * KK * 2;    //  50331648
constexpr size_t WS_BH   = WS_AL + (size_t)MM * KK * 2;    // 100663296
constexpr size_t WS_BL   = WS_BH + (size_t)NN * KK * 2;    // 103809024
constexpr size_t WS_CSQ  = WS_BL + (size_t)NN * KK * 2;    // 106954752
constexpr size_t WS_SLOT = WS_CSQ + (size_t)NN * 4;        // 106962944
constexpr size_t WS_NEED = WS_SLOT + (size_t)MM * 16 * 8;  // 111157248

__device__ __forceinline__ unsigned bc(f16x2 h) {
    return __builtin_bit_cast(unsigned, h);
}

// ---------------- fast path ----------------

// One block = 32 rows x 768 k. Blocks [0, MM/32) convert A; the rest convert B
// and also produce csq (row sum of squares). Same split math as round 3:
// hi = pkrtz(x); lo = pkrtz(x - (float)hi).
__global__ __launch_bounds__(256)
void preconvert_kernel(const float* __restrict__ A, const float* __restrict__ Bc,
                       unsigned short* __restrict__ AhG, unsigned short* __restrict__ AlG,
                       unsigned short* __restrict__ BhG, unsigned short* __restrict__ BlG,
                       float* __restrict__ csq) {
    const int bid = blockIdx.x;
    const bool isB = bid >= (MM / 32);
    const int rowbase = (isB ? bid - MM / 32 : bid) * 32;
    const int tid = threadIdx.x;
    const int row = tid >> 3, kc = tid & 7;      // 32 rows x 8 k-chunks
    const size_t base = (size_t)(rowbase + row) * KK + kc * 8;
    const float* src = (isB ? Bc : A) + base;
    unsigned short* dh = (isB ? BhG : AhG) + base;
    unsigned short* dl = (isB ? BlG : AlG) + base;

    float s = 0.f;
#pragma unroll
    for (int t = 0; t < 12; ++t) {               // 8 floats per iter, k += 64
        float4 v0 = *(const float4*)(src + t * 64);
        float4 v1 = *(const float4*)(src + t * 64 + 4);
        if (isB) {
            s = fmaf(v0.x, v0.x, s); s = fmaf(v0.y, v0.y, s);
            s = fmaf(v0.z, v0.z, s); s = fmaf(v0.w, v0.w, s);
            s = fmaf(v1.x, v1.x, s); s = fmaf(v1.y, v1.y, s);
            s = fmaf(v1.z, v1.z, s); s = fmaf(v1.w, v1.w, s);
        }
        f16x2 h0 = __builtin_amdgcn_cvt_pkrtz(v0.x, v0.y);
        f16x2 h1 = __builtin_amdgcn_cvt_pkrtz(v0.z, v0.w);
        f16x2 h2 = __builtin_amdgcn_cvt_pkrtz(v1.x, v1.y);
        f16x2 h3 = __builtin_amdgcn_cvt_pkrtz(v1.z, v1.w);
        f16x2 l0 = __builtin_amdgcn_cvt_pkrtz(v0.x-(float)h0[0], v0.y-(float)h0[1]);
        f16x2 l1 = __builtin_amdgcn_cvt_pkrtz(v0.z-(float)h1[0], v0.w-(float)h1[1]);
        f16x2 l2 = __builtin_amdgcn_cvt_pkrtz(v1.x-(float)h2[0], v1.y-(float)h2[1]);
        f16x2 l3 = __builtin_amdgcn_cvt_pkrtz(v1.z-(float)h3[0], v1.w-(float)h3[1]);
        uint4 hv = {bc(h0), bc(h1), bc(h2), bc(h3)};
        uint4 lv = {bc(l0), bc(l1), bc(l2), bc(l3)};
        *(uint4*)(dh + t * 64) = hv;
        *(uint4*)(dl + t * 64) = lv;
    }
    if (isB) {
        s += __shfl_xor(s, 1, 64);
        s += __shfl_xor(s, 2, 64);
        s += __shfl_xor(s, 4, 64);
        if (kc == 0) csq[rowbase + row] = s;
    }
}

__global__ __launch_bounds__(256, 2)
void gemm_f16_kernel(const unsigned short* __restrict__ AhG, const unsigned short* __restrict__ AlG,
                     const unsigned short* __restrict__ BhG, const unsigned short* __restrict__ BlG,
                     const float* __restrict__ csq, uint2* __restrict__ slots) {
    // Four f16 tiles [128 rows][32 k] as u32[128][16], row stride 20 u32.
    __shared__ unsigned lds[4 * 128 * 20];   // 40960 B: AH | AL | BH | BL
    constexpr int AH = 0, AL = 2560, BH = 5120, BL = 7680;

    const int tid  = threadIdx.x;
    const int lane = tid & 63;
    const int ln15 = lane & 15;
    const int quad = lane >> 4;
    const int wave = tid >> 6;
    const int wm = wave >> 1, wn = wave & 1;
    const int tbase = blockIdx.x * BM;
    const int cb    = blockIdx.y * BN;

    // Staging: unit u = tid + 256*s (s=0,1): row = u>>2, ku = u&3 (8 f16 = 16 B).
    const int r0 = tid >> 2, ku = tid & 3;
    const uint4* gAh = (const uint4*)AhG;    // row stride RSTR=96 uint4 (f16 row)
    const uint4* gAl = (const uint4*)AlG;
    const uint4* gBh = (const uint4*)BhG;
    const uint4* gBl = (const uint4*)BlG;
    const size_t arow0 = (size_t)(tbase + r0) * RSTR + ku;
    const size_t arow1 = (size_t)(tbase + r0 + 64) * RSTR + ku;
    const size_t brow0 = (size_t)(cb + r0) * RSTR + ku;
    const size_t brow1 = (size_t)(cb + r0 + 64) * RSTR + ku;
    const int sw0 = r0 * 20 + ku * 4;
    const int sw1 = sw0 + 64 * 20;

    f32x4 acc[4][4];
#pragma unroll
    for (int i = 0; i < 4; ++i)
#pragma unroll
        for (int j = 0; j < 4; ++j) { f32x4 z = {0.f,0.f,0.f,0.f}; acc[i][j] = z; }

    // Prologue prefetch of k-tile 0 (k-tile kt -> uint4 col offset kt*4).
    uint4 pAh0 = gAh[arow0], pAh1 = gAh[arow1];
    uint4 pAl0 = gAl[arow0], pAl1 = gAl[arow1];
    uint4 pBh0 = gBh[brow0], pBh1 = gBh[brow1];
    uint4 pBl0 = gBl[brow0], pBl1 = gBl[brow1];

    int aw[4], bw[4];
#pragma unroll
    for (int i = 0; i < 4; ++i) {
        aw[i] = AH + (wm * 64 + i * 16 + ln15) * 20 + quad * 4;
        bw[i] = BH + (wn * 64 + i * 16 + ln15) * 20 + quad * 4;
    }

    for (int kt = 0; kt < KK / BK; ++kt) {
        __syncthreads();
        *(uint4*)&lds[AH + sw0] = pAh0; *(uint4*)&lds[AH + sw1] = pAh1;
        *(uint4*)&lds[AL + sw0] = pAl0; *(uint4*)&lds[AL + sw1] = pAl1;
        *(uint4*)&lds[BH + sw0] = pBh0; *(uint4*)&lds[BH + sw1] = pBh1;
        *(uint4*)&lds[BL + sw0] = pBl0; *(uint4*)&lds[BL + sw1] = pBl1;
        __syncthreads();

        if (kt + 1 < KK / BK) {
            const size_t ko = (size_t)(kt + 1) * 4;
            pAh0 = gAh[arow0 + ko]; pAh1 = gAh[arow1 + ko];
            pAl0 = gAl[arow0 + ko]; pAl1 = gAl[arow1 + ko];
            pBh0 = gBh[brow0 + ko]; pBh1 = gBh[brow1 + ko];
            pBl0 = gBl[brow0 + ko]; pBl1 = gBl[brow1 + ko];
        }

        f16x8 a_h[4], a_l[4], b_h[4], b_l[4];
#pragma unroll
        for (int i = 0; i < 4; ++i) {
            a_h[i] = *(const f16x8*)&lds[aw[i]];
            a_l[i] = *(const f16x8*)&lds[aw[i] + (AL - AH)];
            b_h[i] = *(const f16x8*)&lds[bw[i]];
            b_l[i] = *(const f16x8*)&lds[bw[i] + (BL - BH)];
        }
#pragma unroll
        for (int i = 0; i < 4; ++i)
#pragma unroll
            for (int j = 0; j < 4; ++j) {
                acc[i][j] = __builtin_amdgcn_mfma_f32_16x16x32_f16(a_h[i], b_h[j], acc[i][j], 0, 0, 0);
                acc[i][j] = __builtin_amdgcn_mfma_f32_16x16x32_f16(a_h[i], b_l[j], acc[i][j], 0, 0, 0);
                acc[i][j] = __builtin_amdgcn_mfma_f32_16x16x32_f16(a_l[i], b_h[j], acc[i][j], 0, 0, 0);
            }
    }

    // Epilogue: score = csq - 2*dot; C/D layout col=lane&15, row=quad*4+reg.
    float csq4[4];
#pragma unroll
    for (int j = 0; j < 4; ++j) csq4[j] = csq[cb + wn * 64 + j * 16 + ln15];

    float bval[16]; int bidx[16];
#pragma unroll
    for (int i = 0; i < 4; ++i)
#pragma unroll
        for (int r = 0; r < 4; ++r) {
            const int rid = i * 4 + r;
            float bv_ = csq4[0] - 2.0f * acc[i][0][r];
            int   bi_ = cb + wn * 64 + ln15;
#pragma unroll
            for (int j = 1; j < 4; ++j) {
                const float s = csq4[j] - 2.0f * acc[i][j][r];
                const int   c = cb + wn * 64 + j * 16 + ln15;
                if (s < bv_) { bv_ = s; bi_ = c; }   // ascending c, strict <
            }
            bval[rid] = bv_; bidx[rid] = bi_;
        }
#pragma unroll
    for (int off = 1; off < 16; off <<= 1) {
#pragma unroll
        for (int rid = 0; rid < 16; ++rid) {
            const float ov = __shfl_xor(bval[rid], off, 64);
            const int   oi = __shfl_xor(bidx[rid], off, 64);
            if (ov < bval[rid] || (ov == bval[rid] && oi < bidx[rid])) {
                bval[rid] = ov; bidx[rid] = oi;
            }
        }
    }

    __syncthreads();                 // tiles dead; reuse LDS for row table
    float* vtab = (float*)&lds[0];   // [128][2]
    int*   itab = (int*)&lds[256];   // [128][2]
    if (ln15 == 0) {
#pragma unroll
        for (int i = 0; i < 4; ++i)
#pragma unroll
            for (int r = 0; r < 4; ++r) {
                const int row = wm * 64 + i * 16 + quad * 4 + r;
                vtab[row * 2 + wn] = bval[i * 4 + r];
                itab[row * 2 + wn] = bidx[i * 4 + r];
            }
    }
    __syncthreads();
    if (tid < 128) {
        float v0 = vtab[tid * 2]; int i0 = itab[tid * 2];
        const float v1 = vtab[tid * 2 + 1]; const int i1 = itab[tid * 2 + 1];
        if (v1 < v0 || (v1 == v0 && i1 < i0)) { v0 = v1; i0 = i1; }
        uint2 e; e.x = __float_as_uint(v0); e.y = (unsigned)i0;
        slots[(size_t)(tbase + tid) * 16 + blockIdx.y] = e;   // no atomics
    }
}

__global__ __launch_bounds__(256)
void slot_reduce_kernel(const uint2* __restrict__ slots, int* __restrict__ out) {
    const int t = blockIdx.x * 256 + threadIdx.x;
    const uint2* s = slots + (size_t)t * 16;
    float bv = __uint_as_float(s[0].x); int bi = (int)s[0].y;
#pragma unroll
    for (int j = 1; j < 16; ++j) {
        const uint2 e = s[j];
        const float v = __uint_as_float(e.x);
        if (v < bv || (v == bv && (int)e.y < bi)) { bv = v; bi = (int)e.y; }
    }
    out[t] = bi;
}

// ---------------- round-3 fallback (proven) ----------------

__global__ __launch_bounds__(256)
void init_ws_kernel(unsigned long long* __restrict__ w) {
    w[blockIdx.x * 256 + threadIdx.x] = 0xFFFFFFFFFFFFFFFFull;
}

__global__ __launch_bounds__(64)
void csq_kernel(const float* __restrict__ cc, float* __restrict__ csq) {
    const int cl = blockIdx.x;
    const int lane = threadIdx.x;
    const float4* row = reinterpret_cast<const float4*>(cc + (size_t)cl * KK);
    float s = 0.f;
#pragma unroll
    for (int w = 0; w < KK / (4 * 64); ++w) {
        float4 v = row[w * 64 + lane];
        s = fmaf(v.x, v.x, s); s = fmaf(v.y, v.y, s);
        s = fmaf(v.z, v.z, s); s = fmaf(v.w, v.w, s);
    }
#pragma unroll
    for (int off = 32; off > 0; off >>= 1) s += __shfl_xor(s, off, 64);
    if (lane == 0) csq[cl] = s;
}

__global__ __launch_bounds__(256, 2)
void argmin_mfma_kernel(const float* __restrict__ A, const float* __restrict__ Bc,
                        const float* __restrict__ csq,
                        unsigned long long* __restrict__ ws64) {
    __shared__ unsigned lds[4 * 128 * 20];
    constexpr int AH = 0, AL = 2560, BH = 5120;

    const int tid  = threadIdx.x;
    const int lane = tid & 63;
    const int ln15 = lane & 15;
    const int quad = lane >> 4;
    const int wave = tid >> 6;
    const int wm = wave >> 1, wn = wave & 1;
    const int tbase = blockIdx.x * BM;
    const int cb    = blockIdx.y * BN;

    const int sr  = tid >> 1;
    const int skh = tid & 1;
    const float* gA = A  + (size_t)(tbase + sr) * KK + skh * 16;
    const float* gB = Bc + (size_t)(cb   + sr) * KK + skh * 16;
    const int wword = sr * 20 + skh * 8;

    f32x4 acc[4][4];
#pragma unroll
    for (int i = 0; i < 4; ++i)
#pragma unroll
        for (int j = 0; j < 4; ++j) { f32x4 z = {0.f,0.f,0.f,0.f}; acc[i][j] = z; }

    float4 av[4], bv[4];
#pragma unroll
    for (int p = 0; p < 4; ++p) {
        av[p] = *(const float4*)(gA + p * 4);
        bv[p] = *(const float4*)(gB + p * 4);
    }

    int aw[4], bw[4];
#pragma unroll
    for (int i = 0; i < 4; ++i) {
        aw[i] = AH + (wm * 64 + i * 16 + ln15) * 20 + quad * 4;
        bw[i] = BH + (wn * 64 + i * 16 + ln15) * 20 + quad * 4;
    }

    for (int k0 = 0; k0 < KK; k0 += BK) {
        __syncthreads();
#pragma unroll
        for (int h = 0; h < 2; ++h) {
            float4 v0 = av[2*h], v1 = av[2*h+1];
            f16x2 h00 = __builtin_amdgcn_cvt_pkrtz(v0.x, v0.y);
            f16x2 h01 = __builtin_amdgcn_cvt_pkrtz(v0.z, v0.w);
            f16x2 h10 = __builtin_amdgcn_cvt_pkrtz(v1.x, v1.y);
            f16x2 h11 = __builtin_amdgcn_cvt_pkrtz(v1.z, v1.w);
            f16x2 l00 = __builtin_amdgcn_cvt_pkrtz(v0.x-(float)h00[0], v0.y-(float)h00[1]);
            f16x2 l01 = __builtin_amdgcn_cvt_pkrtz(v0.z-(float)h01[0], v0.w-(float)h01[1]);
            f16x2 l10 = __builtin_amdgcn_cvt_pkrtz(v1.x-(float)h10[0], v1.y-(float)h10[1]);
            f16x2 l11 = __builtin_amdgcn_cvt_pkrtz(v1.z-(float)h11[0], v1.w-(float)h11[1]);
            uint4 hv = {bc(h00), bc(h01), bc(h10), bc(h11)};
            uint4 lv = {bc(l00), bc(l01), bc(l10), bc(l11)};
            *(uint4*)&lds[AH + wword + 4*h] = hv;
            *(uint4*)&lds[AL + wword + 4*h] = lv;

            float4 w0 = bv[2*h], w1 = bv[2*h+1];
            f16x2 g00 = __builtin_amdgcn_cvt_pkrtz(w0.x, w0.y);
            f16x2 g01 = __builtin_amdgcn_cvt_pkrtz(w0.z, w0.w);
            f16x2 g10 = __builtin_amdgcn_cvt_pkrtz(w1.x, w1.y);
            f16x2 g11 = __builtin_amdgcn_cvt_pkrtz(w1.z, w1.w);
            f16x2 m00 = __builtin_amdgcn_cvt_pkrtz(w0.x-(float)g00[0], w0.y-(float)g00[1]);
            f16x2 m01 = __builtin_amdgcn_cvt_pkrtz(w0.z-(float)g01[0], w0.w-(float)g01[1]);
            f16x2 m10 = __builtin_amdgcn_cvt_pkrtz(w1.x-(float)g10[0], w1.y-(float)g10[1]);
            f16x2 m11 = __builtin_amdgcn_cvt_pkrtz(w1.z-(float)g11[0], w1.w-(float)g11[1]);
            uint4 gv = {bc(g00), bc(g01), bc(g10), bc(g11)};
            uint4 mv = {bc(m00), bc(m01), bc(m10), bc(m11)};
            *(uint4*)&lds[BH + wword + 4*h]        = gv;
            *(uint4*)&lds[BH + 2560 + wword + 4*h] = mv;
        }
        __syncthreads();

        const int kn = k0 + BK;
        if (kn < KK) {
#pragma unroll
            for (int p = 0; p < 4; ++p) {
                av[p] = *(const float4*)(gA + kn + p * 4);
                bv[p] = *(const float4*)(gB + kn + p * 4);
            }
        }

        f16x8 a_h[4], a_l[4], b_h[4], b_l[4];
#pragma unroll
        for (int i = 0; i < 4; ++i) {
            a_h[i] = *(const f16x8*)&lds[aw[i]];
            a_l[i] = *(const f16x8*)&lds[aw[i] + 2560];
            b_h[i] = *(const f16x8*)&lds[bw[i]];
            b_l[i] = *(const f16x8*)&lds[bw[i] + 2560];
        }
#pragma unroll
        for (int i = 0; i < 4; ++i)
#pragma unroll
            for (int j = 0; j < 4; ++j) {
                acc[i][j] = __builtin_amdgcn_mfma_f32_16x16x32_f16(a_h[i], b_h[j], acc[i][j], 0, 0, 0);
                acc[i][j] = __builtin_amdgcn_mfma_f32_16x16x32_f16(a_h[i], b_l[j], acc[i][j], 0, 0, 0);
                acc[i][j] = __builtin_amdgcn_mfma_f32_16x16x32_f16(a_l[i], b_h[j], acc[i][j], 0, 0, 0);
            }
    }

    float csq4[4];
#pragma unroll
    for (int j = 0; j < 4; ++j) csq4[j] = csq[cb + wn * 64 + j * 16 + ln15];

    float bval[16]; int bidx[16];
#pragma unroll
    for (int i = 0; i < 4; ++i)
#pragma unroll
        for (int r = 0; r < 4; ++r) {
            const int rid = i * 4 + r;
            float bv_ = csq4[0] - 2.0f * acc[i][0][r];
            int   bi_ = cb + wn * 64 + ln15;
#pragma unroll
            for (int j = 1; j < 4; ++j) {
                const float s = csq4[j] - 2.0f * acc[i][j][r];
                const int   c = cb + wn * 64 + j * 16 + ln15;
                if (s < bv_) { bv_ = s; bi_ = c; }
            }
            bval[rid] = bv_; bidx[rid] = bi_;
        }
#pragma unroll
    for (int off = 1; off < 16; off <<= 1) {
#pragma unroll
        for (int rid = 0; rid < 16; ++rid) {
            const float ov = __shfl_xor(bval[rid], off, 64);
            const int   oi = __shfl_xor(bidx[rid], off, 64);
            if (ov < bval[rid] || (ov == bval[rid] && oi < bidx[rid])) {
                bval[rid] = ov; bidx[rid] = oi;
            }
        }
    }

    __syncthreads();
    float* vtab = (float*)&lds[0];
    int*   itab = (int*)&lds[256];
    if (ln15 == 0) {
#pragma unroll
        for (int i = 0; i < 4; ++i)
#pragma unroll
            for (int r = 0; r < 4; ++r) {
                const int row = wm * 64 + i * 16 + quad * 4 + r;
                vtab[row * 2 + wn] = bval[i * 4 + r];
                itab[row * 2 + wn] = bidx[i * 4 + r];
            }
    }
    __syncthreads();
    if (tid < 128) {
        float v0 = vtab[tid * 2]; int i0 = itab[tid * 2];
        const float v1 = vtab[tid * 2 + 1]; const int i1 = itab[tid * 2 + 1];
        if (v1 < v0 || (v1 == v0 && i1 < i0)) { v0 = v1; i0 = i1; }
        const unsigned b   = __float_as_uint(v0);
        const unsigned key = (b & 0x80000000u) ? ~b : (b | 0x80000000u);
        const unsigned long long pk =
            ((unsigned long long)key << 32) | (unsigned long long)(unsigned)i0;
        atomicMin(&ws64[tbase + tid], pk);
    }
}

__global__ __launch_bounds__(256)
void unpack_kernel(const unsigned long long* __restrict__ w, int* __restrict__ out) {
    const int i = blockIdx.x * 256 + threadIdx.x;
    out[i] = (int)(unsigned)(w[i] & 0xFFFFFFFFull);
}

extern "C" void kernel_launch(void* const* d_in, const int* in_sizes, int n_in,
                              void* d_out, int out_size, void* d_ws, size_t ws_size,
                              hipStream_t stream) {
    const float* embed   = (const float*)d_in[0];   // [32768][768] fp32
    const float* centers = (const float*)d_in[1];   // [2048][768] fp32
    int* out = (int*)d_out;                         // [32768] int32

    if (ws_size >= WS_NEED) {
        unsigned short* Ah = (unsigned short*)((char*)d_ws + WS_AH);
        unsigned short* Al = (unsigned short*)((char*)d_ws + WS_AL);
        unsigned short* Bh = (unsigned short*)((char*)d_ws + WS_BH);
        unsigned short* Bl = (unsigned short*)((char*)d_ws + WS_BL);
        float* csq   = (float*)((char*)d_ws + WS_CSQ);
        uint2* slots = (uint2*)((char*)d_ws + WS_SLOT);
        preconvert_kernel<<<MM / 32 + NN / 32, 256, 0, stream>>>(
            embed, centers, Ah, Al, Bh, Bl, csq);
        gemm_f16_kernel<<<dim3(MM / BM, NN / BN), 256, 0, stream>>>(
            Ah, Al, Bh, Bl, csq, slots);
        slot_reduce_kernel<<<MM / 256, 256, 0, stream>>>(slots, out);
    } else {
        unsigned long long* ws64 = (unsigned long long*)d_ws;
        float* csq = (float*)((char*)d_ws + (size_t)MM * 8);
        init_ws_kernel<<<MM / 256, 256, 0, stream>>>(ws64);
        csq_kernel<<<NN, 64, 0, stream>>>(centers, csq);
        argmin_mfma_kernel<<<dim3(MM / BM, NN / BN), 256, 0, stream>>>(
            embed, centers, csq, ws64);
        unpack_kernel<<<MM / 256, 256, 0, stream>>>(ws64, out);
    }
}

// Round 6
// 452.725 us; speedup vs baseline: 1.0934x; 1.0934x over previous
//
#include <hip/hip_runtime.h>

// argmin_c ||x-c|| == argmin_c (||c||^2 - 2 x.c). Cross-term via 3 f16 MFMA
// GEMMs (exact hi/lo split of fp32, lo*lo dropped ~2^-22 rel).
// Round 6: barrier-free GEMM. Preconvert packs A/B into MFMA *fragment order*
// (1KB units: 16 rows x 32 k x {hi,lo}), so the GEMM K-loop is pure
// global_load_dwordx4 -> MFMA with register ping-pong prefetch. No LDS tiles,
// no __syncthreads, no bank conflicts in the K-loop (round-5 structure was
// barrier/latency-bound at MfmaUtil 42% with every pipe underloaded).
typedef __fp16 f16x2 __attribute__((ext_vector_type(2)));
typedef __fp16 f16x8 __attribute__((ext_vector_type(8)));
typedef float f32x4 __attribute__((ext_vector_type(4)));

constexpr int MM = 32768;   // B*T tokens
constexpr int NN = 2048;    // clusters
constexpr int KK = 768;     // dim
constexpr int BM = 128;     // tokens per block
constexpr int BN = 128;     // clusters per block
constexpr int NKT = KK / 32;          // 24 k-tiles
constexpr int NA_UNITS = (MM / 16) * NKT;   // 49152 A (mt,kt) wave-tasks
constexpr int NB_UNITS = (NN / 16) * NKT;   //  3072 B (nt,kt) wave-tasks

// Workspace layout (bytes). Apack: [mt][kt][part] 1KB units; Bpack same.
constexpr size_t WS_APACK = 0;
constexpr size_t WS_BPACK = WS_APACK + (size_t)MM * KK * 4;  // 100663296
constexpr size_t WS_CSQ   = WS_BPACK + (size_t)NN * KK * 4;  // 106954752
constexpr size_t WS_SLOT  = WS_CSQ + (size_t)NN * 4;         // 106962944
constexpr size_t WS_NEED  = WS_SLOT + (size_t)MM * 16 * 8;   // 111157248

__device__ __forceinline__ unsigned bc(f16x2 h) {
    return __builtin_bit_cast(unsigned, h);
}

// ---------------- fast path ----------------

// One wave packs one (tile16, ktile32, {hi,lo}) pair: reads 16 rows x 128B of
// fp32, writes two contiguous 1KB units in fragment order
// (byte off = (quad*16 + ln15)*16 holds elements m=ln15, k=quad*8..+7).
__global__ __launch_bounds__(256)
void fragpack_kernel(const float* __restrict__ A, const float* __restrict__ Bc,
                     uint4* __restrict__ Ap, uint4* __restrict__ Bp) {
    const int task = blockIdx.x * 4 + (threadIdx.x >> 6);
    const int lane = threadIdx.x & 63;
    const int ln15 = lane & 15;
    const int quad = lane >> 4;

    const bool isB = task >= NA_UNITS;
    const int t = isB ? task - NA_UNITS : task;
    const int tile = t / NKT, kt = t % NKT;
    const float* src = (isB ? Bc : A) + (size_t)(tile * 16 + ln15) * KK + kt * 32 + quad * 8;
    uint4* dst = (isB ? Bp : Ap) + (size_t)t * 128 + lane;   // 2 units = 128 uint4

    const float4 v0 = *(const float4*)(src);
    const float4 v1 = *(const float4*)(src + 4);
    f16x2 h0 = __builtin_amdgcn_cvt_pkrtz(v0.x, v0.y);
    f16x2 h1 = __builtin_amdgcn_cvt_pkrtz(v0.z, v0.w);
    f16x2 h2 = __builtin_amdgcn_cvt_pkrtz(v1.x, v1.y);
    f16x2 h3 = __builtin_amdgcn_cvt_pkrtz(v1.z, v1.w);
    f16x2 l0 = __builtin_amdgcn_cvt_pkrtz(v0.x-(float)h0[0], v0.y-(float)h0[1]);
    f16x2 l1 = __builtin_amdgcn_cvt_pkrtz(v0.z-(float)h1[0], v0.w-(float)h1[1]);
    f16x2 l2 = __builtin_amdgcn_cvt_pkrtz(v1.x-(float)h2[0], v1.y-(float)h2[1]);
    f16x2 l3 = __builtin_amdgcn_cvt_pkrtz(v1.z-(float)h3[0], v1.w-(float)h3[1]);
    uint4 hv = {bc(h0), bc(h1), bc(h2), bc(h3)};
    uint4 lv = {bc(l0), bc(l1), bc(l2), bc(l3)};
    dst[0]  = hv;
    dst[64] = lv;
}

__global__ __launch_bounds__(64)
void csq_kernel(const float* __restrict__ cc, float* __restrict__ csq) {
    const int cl = blockIdx.x;
    const int lane = threadIdx.x;
    const float4* row = reinterpret_cast<const float4*>(cc + (size_t)cl * KK);
    float s = 0.f;
#pragma unroll
    for (int w = 0; w < KK / (4 * 64); ++w) {
        float4 v = row[w * 64 + lane];
        s = fmaf(v.x, v.x, s); s = fmaf(v.y, v.y, s);
        s = fmaf(v.z, v.z, s); s = fmaf(v.w, v.w, s);
    }
#pragma unroll
    for (int off = 32; off > 0; off >>= 1) s += __shfl_xor(s, off, 64);
    if (lane == 0) csq[cl] = s;
}

#define MF(a, b, c) __builtin_amdgcn_mfma_f32_16x16x32_f16( \
    __builtin_bit_cast(f16x8, a), __builtin_bit_cast(f16x8, b), c, 0, 0, 0)

__global__ __launch_bounds__(256, 2)
void gemm_pack_kernel(const uint4* __restrict__ Ap, const uint4* __restrict__ Bp,
                      const float* __restrict__ csq, uint2* __restrict__ slots) {
    const int gx = blockIdx.x;            // n-block 0..15 (fast-varying: co-dispatch
    const int gy = blockIdx.y;            // the 16 blocks sharing one A tile)
    const int tid  = threadIdx.x;
    const int lane = tid & 63;
    const int ln15 = lane & 15;
    const int quad = lane >> 4;
    const int wave = tid >> 6;
    const int wm = wave >> 1, wn = wave & 1;
    const int tbase = gy * BM;
    const int cb    = gx * BN;

    // Fragment unit pointers (uint4 granularity; unit = 64 uint4; kt step = 128).
    const uint4* a_ptr[4];
    const uint4* b_ptr[4];
#pragma unroll
    for (int i = 0; i < 4; ++i) {
        a_ptr[i] = Ap + (size_t)(gy * 8 + wm * 4 + i) * NKT * 128 + lane;
        b_ptr[i] = Bp + (size_t)(gx * 8 + wn * 4 + i) * NKT * 128 + lane;
    }

    f32x4 acc[4][4];
#pragma unroll
    for (int i = 0; i < 4; ++i)
#pragma unroll
        for (int j = 0; j < 4; ++j) { f32x4 z = {0.f,0.f,0.f,0.f}; acc[i][j] = z; }

    uint4 Ah0[4], Al0[4], Bh0[4], Bl0[4];
    uint4 Ah1[4], Al1[4], Bh1[4], Bl1[4];

    auto load0 = [&](int kt) {
        const int o = kt * 128;
#pragma unroll
        for (int i = 0; i < 4; ++i) {
            Ah0[i] = a_ptr[i][o]; Al0[i] = a_ptr[i][o + 64];
            Bh0[i] = b_ptr[i][o]; Bl0[i] = b_ptr[i][o + 64];
        }
    };
    auto load1 = [&](int kt) {
        const int o = kt * 128;
#pragma unroll
        for (int i = 0; i < 4; ++i) {
            Ah1[i] = a_ptr[i][o]; Al1[i] = a_ptr[i][o + 64];
            Bh1[i] = b_ptr[i][o]; Bl1[i] = b_ptr[i][o + 64];
        }
    };
    auto comp0 = [&]() {
#pragma unroll
        for (int i = 0; i < 4; ++i)
#pragma unroll
            for (int j = 0; j < 4; ++j) {
                acc[i][j] = MF(Ah0[i], Bh0[j], acc[i][j]);
                acc[i][j] = MF(Ah0[i], Bl0[j], acc[i][j]);
                acc[i][j] = MF(Al0[i], Bh0[j], acc[i][j]);
            }
    };
    auto comp1 = [&]() {
#pragma unroll
        for (int i = 0; i < 4; ++i)
#pragma unroll
            for (int j = 0; j < 4; ++j) {
                acc[i][j] = MF(Ah1[i], Bh1[j], acc[i][j]);
                acc[i][j] = MF(Ah1[i], Bl1[j], acc[i][j]);
                acc[i][j] = MF(Al1[i], Bh1[j], acc[i][j]);
            }
    };

    load0(0);
#pragma unroll 1
    for (int kt = 0; kt < NKT; kt += 2) {       // no barriers anywhere
        load1(kt + 1);                          // prefetch while comp0's loads drain
        comp0();
        if (kt + 2 < NKT) load0(kt + 2);
        comp1();
    }

    // Epilogue: score = csq - 2*dot; C/D layout col=lane&15, row=quad*4+reg.
    float csq4[4];
#pragma unroll
    for (int j = 0; j < 4; ++j) csq4[j] = csq[cb + wn * 64 + j * 16 + ln15];

    float bval[16]; int bidx[16];
#pragma unroll
    for (int i = 0; i < 4; ++i)
#pragma unroll
        for (int r = 0; r < 4; ++r) {
            const int rid = i * 4 + r;
            float bv_ = csq4[0] - 2.0f * acc[i][0][r];
            int   bi_ = cb + wn * 64 + ln15;
#pragma unroll
            for (int j = 1; j < 4; ++j) {
                const float s = csq4[j] - 2.0f * acc[i][j][r];
                const int   c = cb + wn * 64 + j * 16 + ln15;
                if (s < bv_) { bv_ = s; bi_ = c; }   // ascending c, strict <
            }
            bval[rid] = bv_; bidx[rid] = bi_;
        }
#pragma unroll
    for (int off = 1; off < 16; off <<= 1) {
#pragma unroll
        for (int rid = 0; rid < 16; ++rid) {
            const float ov = __shfl_xor(bval[rid], off, 64);
            const int   oi = __shfl_xor(bidx[rid], off, 64);
            if (ov < bval[rid] || (ov == bval[rid] && oi < bidx[rid])) {
                bval[rid] = ov; bidx[rid] = oi;
            }
        }
    }

    __shared__ float vtab[256];   // [128 rows][2 wn]
    __shared__ int   itab[256];
    if (ln15 == 0) {
#pragma unroll
        for (int i = 0; i < 4; ++i)
#pragma unroll
            for (int r = 0; r < 4; ++r) {
                const int row = wm * 64 + i * 16 + quad * 4 + r;
                vtab[row * 2 + wn] = bval[i * 4 + r];
                itab[row * 2 + wn] = bidx[i * 4 + r];
            }
    }
    __syncthreads();
    if (tid < 128) {
        float v0 = vtab[tid * 2]; int i0 = itab[tid * 2];
        const float v1 = vtab[tid * 2 + 1]; const int i1 = itab[tid * 2 + 1];
        if (v1 < v0 || (v1 == v0 && i1 < i0)) { v0 = v1; i0 = i1; }
        uint2 e; e.x = __float_as_uint(v0); e.y = (unsigned)i0;
        slots[(size_t)(tbase + tid) * 16 + gx] = e;
    }
}

__global__ __launch_bounds__(256)
void slot_reduce_kernel(const uint2* __restrict__ slots, int* __restrict__ out) {
    const int t = blockIdx.x * 256 + threadIdx.x;
    const uint2* s = slots + (size_t)t * 16;
    float bv = __uint_as_float(s[0].x); int bi = (int)s[0].y;
#pragma unroll
    for (int j = 1; j < 16; ++j) {
        const uint2 e = s[j];
        const float v = __uint_as_float(e.x);
        if (v < bv || (v == bv && (int)e.y < bi)) { bv = v; bi = (int)e.y; }
    }
    out[t] = bi;
}

// ---------------- round-3 fallback (proven, used only if ws too small) ------

__global__ __launch_bounds__(256)
void init_ws_kernel(unsigned long long* __restrict__ w) {
    w[blockIdx.x * 256 + threadIdx.x] = 0xFFFFFFFFFFFFFFFFull;
}

__global__ __launch_bounds__(256, 2)
void argmin_mfma_kernel(const float* __restrict__ A, const float* __restrict__ Bc,
                        const float* __restrict__ csq,
                        unsigned long long* __restrict__ ws64) {
    __shared__ unsigned lds[4 * 128 * 20];
    constexpr int AH = 0, AL = 2560, BH = 5120;

    const int tid  = threadIdx.x;
    const int lane = tid & 63;
    const int ln15 = lane & 15;
    const int quad = lane >> 4;
    const int wave = tid >> 6;
    const int wm = wave >> 1, wn = wave & 1;
    const int tbase = blockIdx.x * BM;
    const int cb    = blockIdx.y * BN;

    const int sr  = tid >> 1;
    const int skh = tid & 1;
    const float* gA = A  + (size_t)(tbase + sr) * KK + skh * 16;
    const float* gB = Bc + (size_t)(cb   + sr) * KK + skh * 16;
    const int wword = sr * 20 + skh * 8;

    f32x4 acc[4][4];
#pragma unroll
    for (int i = 0; i < 4; ++i)
#pragma unroll
        for (int j = 0; j < 4; ++j) { f32x4 z = {0.f,0.f,0.f,0.f}; acc[i][j] = z; }

    float4 av[4], bv[4];
#pragma unroll
    for (int p = 0; p < 4; ++p) {
        av[p] = *(const float4*)(gA + p * 4);
        bv[p] = *(const float4*)(gB + p * 4);
    }

    int aw[4], bw[4];
#pragma unroll
    for (int i = 0; i < 4; ++i) {
        aw[i] = AH + (wm * 64 + i * 16 + ln15) * 20 + quad * 4;
        bw[i] = BH + (wn * 64 + i * 16 + ln15) * 20 + quad * 4;
    }

    for (int k0 = 0; k0 < KK; k0 += 32) {
        __syncthreads();
#pragma unroll
        for (int h = 0; h < 2; ++h) {
            float4 v0 = av[2*h], v1 = av[2*h+1];
            f16x2 h00 = __builtin_amdgcn_cvt_pkrtz(v0.x, v0.y);
            f16x2 h01 = __builtin_amdgcn_cvt_pkrtz(v0.z, v0.w);
            f16x2 h10 = __builtin_amdgcn_cvt_pkrtz(v1.x, v1.y);
            f16x2 h11 = __builtin_amdgcn_cvt_pkrtz(v1.z, v1.w);
            f16x2 l00 = __builtin_amdgcn_cvt_pkrtz(v0.x-(float)h00[0], v0.y-(float)h00[1]);
            f16x2 l01 = __builtin_amdgcn_cvt_pkrtz(v0.z-(float)h01[0], v0.w-(float)h01[1]);
            f16x2 l10 = __builtin_amdgcn_cvt_pkrtz(v1.x-(float)h10[0], v1.y-(float)h10[1]);
            f16x2 l11 = __builtin_amdgcn_cvt_pkrtz(v1.z-(float)h11[0], v1.w-(float)h11[1]);
            uint4 hv = {bc(h00), bc(h01), bc(h10), bc(h11)};
            uint4 lv = {bc(l00), bc(l01), bc(l10), bc(l11)};
            *(uint4*)&lds[AH + wword + 4*h] = hv;
            *(uint4*)&lds[AL + wword + 4*h] = lv;

            float4 w0 = bv[2*h], w1 = bv[2*h+1];
            f16x2 g00 = __builtin_amdgcn_cvt_pkrtz(w0.x, w0.y);
            f16x2 g01 = __builtin_amdgcn_cvt_pkrtz(w0.z, w0.w);
            f16x2 g10 = __builtin_amdgcn_cvt_pkrtz(w1.x, w1.y);
            f16x2 g11 = __builtin_amdgcn_cvt_pkrtz(w1.z, w1.w);
            f16x2 m00 = __builtin_amdgcn_cvt_pkrtz(w0.x-(float)g00[0], w0.y-(float)g00[1]);
            f16x2 m01 = __builtin_amdgcn_cvt_pkrtz(w0.z-(float)g01[0], w0.w-(float)g01[1]);
            f16x2 m10 = __builtin_amdgcn_cvt_pkrtz(w1.x-(float)g10[0], w1.y-(float)g10[1]);
            f16x2 m11 = __builtin_amdgcn_cvt_pkrtz(w1.z-(float)g11[0], w1.w-(float)g11[1]);
            uint4 gv = {bc(g00), bc(g01), bc(g10), bc(g11)};
            uint4 mv = {bc(m00), bc(m01), bc(m10), bc(m11)};
            *(uint4*)&lds[BH + wword + 4*h]        = gv;
            *(uint4*)&lds[BH + 2560 + wword + 4*h] = mv;
        }
        __syncthreads();

        const int kn = k0 + 32;
        if (kn < KK) {
#pragma unroll
            for (int p = 0; p < 4; ++p) {
                av[p] = *(const float4*)(gA + kn + p * 4);
                bv[p] = *(const float4*)(gB + kn + p * 4);
            }
        }

        f16x8 a_h[4], a_l[4], b_h[4], b_l[4];
#pragma unroll
        for (int i = 0; i < 4; ++i) {
            a_h[i] = *(const f16x8*)&lds[aw[i]];
            a_l[i] = *(const f16x8*)&lds[aw[i] + 2560];
            b_h[i] = *(const f16x8*)&lds[bw[i]];
            b_l[i] = *(const f16x8*)&lds[bw[i] + 2560];
        }
#pragma unroll
        for (int i = 0; i < 4; ++i)
#pragma unroll
            for (int j = 0; j < 4; ++j) {
                acc[i][j] = __builtin_amdgcn_mfma_f32_16x16x32_f16(a_h[i], b_h[j], acc[i][j], 0, 0, 0);
                acc[i][j] = __builtin_amdgcn_mfma_f32_16x16x32_f16(a_h[i], b_l[j], acc[i][j], 0, 0, 0);
                acc[i][j] = __builtin_amdgcn_mfma_f32_16x16x32_f16(a_l[i], b_h[j], acc[i][j], 0, 0, 0);
            }
    }

    float csq4[4];
#pragma unroll
    for (int j = 0; j < 4; ++j) csq4[j] = csq[cb + wn * 64 + j * 16 + ln15];

    float bval[16]; int bidx[16];
#pragma unroll
    for (int i = 0; i < 4; ++i)
#pragma unroll
        for (int r = 0; r < 4; ++r) {
            const int rid = i * 4 + r;
            float bv_ = csq4[0] - 2.0f * acc[i][0][r];
            int   bi_ = cb + wn * 64 + ln15;
#pragma unroll
            for (int j = 1; j < 4; ++j) {
                const float s = csq4[j] - 2.0f * acc[i][j][r];
                const int   c = cb + wn * 64 + j * 16 + ln15;
                if (s < bv_) { bv_ = s; bi_ = c; }
            }
            bval[rid] = bv_; bidx[rid] = bi_;
        }
#pragma unroll
    for (int off = 1; off < 16; off <<= 1) {
#pragma unroll
        for (int rid = 0; rid < 16; ++rid) {
            const float ov = __shfl_xor(bval[rid], off, 64);
            const int   oi = __shfl_xor(bidx[rid], off, 64);
            if (ov < bval[rid] || (ov == bval[rid] && oi < bidx[rid])) {
                bval[rid] = ov; bidx[rid] = oi;
            }
        }
    }

    __syncthreads();
    float* vtab = (float*)&lds[0];
    int*   itab = (int*)&lds[256];
    if (ln15 == 0) {
#pragma unroll
        for (int i = 0; i < 4; ++i)
#pragma unroll
            for (int r = 0; r < 4; ++r) {
                const int row = wm * 64 + i * 16 + quad * 4 + r;
                vtab[row * 2 + wn] = bval[i * 4 + r];
                itab[row * 2 + wn] = bidx[i * 4 + r];
            }
    }
    __syncthreads();
    if (tid < 128) {
        float v0 = vtab[tid * 2]; int i0 = itab[tid * 2];
        const float v1 = vtab[tid * 2 + 1]; const int i1 = itab[tid * 2 + 1];
        if (v1 < v0 || (v1 == v0 && i1 < i0)) { v0 = v1; i0 = i1; }
        const unsigned b   = __float_as_uint(v0);
        const unsigned key = (b & 0x80000000u) ? ~b : (b | 0x80000000u);
        const unsigned long long pk =
            ((unsigned long long)key << 32) | (unsigned long long)(unsigned)i0;
        atomicMin(&ws64[tbase + tid], pk);
    }
}

__global__ __launch_bounds__(256)
void unpack_kernel(const unsigned long long* __restrict__ w, int* __restrict__ out) {
    const int i = blockIdx.x * 256 + threadIdx.x;
    out[i] = (int)(unsigned)(w[i] & 0xFFFFFFFFull);
}

extern "C" void kernel_launch(void* const* d_in, const int* in_sizes, int n_in,
                              void* d_out, int out_size, void* d_ws, size_t ws_size,
                              hipStream_t stream) {
    const float* embed   = (const float*)d_in[0];   // [32768][768] fp32
    const float* centers = (const float*)d_in[1];   // [2048][768] fp32
    int* out = (int*)d_out;                         // [32768] int32

    if (ws_size >= WS_NEED) {
        uint4* Ap = (uint4*)((char*)d_ws + WS_APACK);
        uint4* Bp = (uint4*)((char*)d_ws + WS_BPACK);
        float* csq   = (float*)((char*)d_ws + WS_CSQ);
        uint2* slots = (uint2*)((char*)d_ws + WS_SLOT);
        fragpack_kernel<<<(NA_UNITS + NB_UNITS) / 4, 256, 0, stream>>>(
            embed, centers, Ap, Bp);
        csq_kernel<<<NN, 64, 0, stream>>>(centers, csq);
        gemm_pack_kernel<<<dim3(NN / BN, MM / BM), 256, 0, stream>>>(
            Ap, Bp, csq, slots);
        slot_reduce_kernel<<<MM / 256, 256, 0, stream>>>(slots, out);
    } else {
        unsigned long long* ws64 = (unsigned long long*)d_ws;
        float* csq = (float*)((char*)d_ws + (size_t)MM * 8);
        init_ws_kernel<<<MM / 256, 256, 0, stream>>>(ws64);
        csq_kernel<<<NN, 64, 0, stream>>>(centers, csq);
        argmin_mfma_kernel<<<dim3(MM / BM, NN / BN), 256, 0, stream>>>(
            embed, centers, csq, ws64);
        unpack_kernel<<<MM / 256, 256, 0, stream>>>(ws64, out);
    }
}

// Round 7
// 443.973 us; speedup vs baseline: 1.1150x; 1.0197x over previous
//
#include <hip/hip_runtime.h>

// argmin_c ||x-c|| == argmin_c (||c||^2 - 2 x.c). Cross-term via 3 f16 MFMA
// GEMMs (exact hi/lo split of fp32, lo*lo dropped ~2^-22 rel).
// Round 7: XCD-aware block swizzle. Round-6 counters showed 4x HBM over-fetch
// (428 MB vs 107 unique): the 16 blocks sharing an A tile were round-robined
// across 8 non-coherent XCD L2s. Spacing them 8 apart in dispatch order pins
// each A tile to one XCD -> K-loop loads become L2-resident -> latency drops
// from ~L3/HBM (500-900 cyc) to ~L2 (200 cyc), which the 1-deep ping-pong
// plus co-resident waves can actually hide. B loads issued first (L3-resident,
// longer latency); A loads (L2) last.
typedef __fp16 f16x2 __attribute__((ext_vector_type(2)));
typedef __fp16 f16x8 __attribute__((ext_vector_type(8)));
typedef float f32x4 __attribute__((ext_vector_type(4)));

constexpr int MM = 32768;   // B*T tokens
constexpr int NN = 2048;    // clusters
constexpr int KK = 768;     // dim
constexpr int BM = 128;     // tokens per block
constexpr int BN = 128;     // clusters per block
constexpr int NKT = KK / 32;          // 24 k-tiles
constexpr int NA_UNITS = (MM / 16) * NKT;   // 49152 A (mt,kt) wave-tasks
constexpr int NB_UNITS = (NN / 16) * NKT;   //  3072 B (nt,kt) wave-tasks

// Workspace layout (bytes). Apack: [mt][kt][part] 1KB units; Bpack same.
constexpr size_t WS_APACK = 0;
constexpr size_t WS_BPACK = WS_APACK + (size_t)MM * KK * 4;  // 100663296
constexpr size_t WS_CSQ   = WS_BPACK + (size_t)NN * KK * 4;  // 106954752
constexpr size_t WS_SLOT  = WS_CSQ + (size_t)NN * 4;         // 106962944
constexpr size_t WS_NEED  = WS_SLOT + (size_t)MM * 16 * 8;   // 111157248

__device__ __forceinline__ unsigned bc(f16x2 h) {
    return __builtin_bit_cast(unsigned, h);
}

// ---------------- fast path ----------------

// One wave packs one (tile16, ktile32, {hi,lo}) pair: reads 16 rows x 128B of
// fp32, writes two contiguous 1KB units in fragment order
// (byte off = (quad*16 + ln15)*16 holds elements m=ln15, k=quad*8..+7).
__global__ __launch_bounds__(256)
void fragpack_kernel(const float* __restrict__ A, const float* __restrict__ Bc,
                     uint4* __restrict__ Ap, uint4* __restrict__ Bp) {
    const int task = blockIdx.x * 4 + (threadIdx.x >> 6);
    const int lane = threadIdx.x & 63;
    const int ln15 = lane & 15;
    const int quad = lane >> 4;

    const bool isB = task >= NA_UNITS;
    const int t = isB ? task - NA_UNITS : task;
    const int tile = t / NKT, kt = t % NKT;
    const float* src = (isB ? Bc : A) + (size_t)(tile * 16 + ln15) * KK + kt * 32 + quad * 8;
    uint4* dst = (isB ? Bp : Ap) + (size_t)t * 128 + lane;   // 2 units = 128 uint4

    const float4 v0 = *(const float4*)(src);
    const float4 v1 = *(const float4*)(src + 4);
    f16x2 h0 = __builtin_amdgcn_cvt_pkrtz(v0.x, v0.y);
    f16x2 h1 = __builtin_amdgcn_cvt_pkrtz(v0.z, v0.w);
    f16x2 h2 = __builtin_amdgcn_cvt_pkrtz(v1.x, v1.y);
    f16x2 h3 = __builtin_amdgcn_cvt_pkrtz(v1.z, v1.w);
    f16x2 l0 = __builtin_amdgcn_cvt_pkrtz(v0.x-(float)h0[0], v0.y-(float)h0[1]);
    f16x2 l1 = __builtin_amdgcn_cvt_pkrtz(v0.z-(float)h1[0], v0.w-(float)h1[1]);
    f16x2 l2 = __builtin_amdgcn_cvt_pkrtz(v1.x-(float)h2[0], v1.y-(float)h2[1]);
    f16x2 l3 = __builtin_amdgcn_cvt_pkrtz(v1.z-(float)h3[0], v1.w-(float)h3[1]);
    uint4 hv = {bc(h0), bc(h1), bc(h2), bc(h3)};
    uint4 lv = {bc(l0), bc(l1), bc(l2), bc(l3)};
    dst[0]  = hv;
    dst[64] = lv;
}

__global__ __launch_bounds__(64)
void csq_kernel(const float* __restrict__ cc, float* __restrict__ csq) {
    const int cl = blockIdx.x;
    const int lane = threadIdx.x;
    const float4* row = reinterpret_cast<const float4*>(cc + (size_t)cl * KK);
    float s = 0.f;
#pragma unroll
    for (int w = 0; w < KK / (4 * 64); ++w) {
        float4 v = row[w * 64 + lane];
        s = fmaf(v.x, v.x, s); s = fmaf(v.y, v.y, s);
        s = fmaf(v.z, v.z, s); s = fmaf(v.w, v.w, s);
    }
#pragma unroll
    for (int off = 32; off > 0; off >>= 1) s += __shfl_xor(s, off, 64);
    if (lane == 0) csq[cl] = s;
}

#define MF(a, b, c) __builtin_amdgcn_mfma_f32_16x16x32_f16( \
    __builtin_bit_cast(f16x8, a), __builtin_bit_cast(f16x8, b), c, 0, 0, 0)

__global__ __launch_bounds__(256, 2)
void gemm_pack_kernel(const uint4* __restrict__ Ap, const uint4* __restrict__ Bp,
                      const float* __restrict__ csq, uint2* __restrict__ slots) {
    // XCD-aware swizzle: xcd = b&7 (round-robin dispatch); the 16 gx-blocks
    // sharing one A tile (same gy) get ids base+8j -> same XCD -> A tile is
    // that XCD's-L2-resident after first touch.
    const int b   = blockIdx.x;
    const int xcd = b & 7;
    const int s   = b >> 3;            // 0..511 sequence within XCD
    const int gx  = s & 15;            // n-block
    const int gy  = xcd + ((s >> 4) << 3);   // m-block 0..255

    const int tid  = threadIdx.x;
    const int lane = tid & 63;
    const int ln15 = lane & 15;
    const int quad = lane >> 4;
    const int wave = tid >> 6;
    const int wm = wave >> 1, wn = wave & 1;
    const int tbase = gy * BM;
    const int cb    = gx * BN;

    // Fragment unit pointers (uint4 granularity; unit = 64 uint4; kt step = 128).
    const uint4* a_ptr[4];
    const uint4* b_ptr[4];
#pragma unroll
    for (int i = 0; i < 4; ++i) {
        a_ptr[i] = Ap + (size_t)(gy * 8 + wm * 4 + i) * NKT * 128 + lane;
        b_ptr[i] = Bp + (size_t)(gx * 8 + wn * 4 + i) * NKT * 128 + lane;
    }

    f32x4 acc[4][4];
#pragma unroll
    for (int i = 0; i < 4; ++i)
#pragma unroll
        for (int j = 0; j < 4; ++j) { f32x4 z = {0.f,0.f,0.f,0.f}; acc[i][j] = z; }

    uint4 Ah0[4], Al0[4], Bh0[4], Bl0[4];
    uint4 Ah1[4], Al1[4], Bh1[4], Bl1[4];

    // B first (L3-resident, longer latency), A last (L2-resident after swizzle).
    auto load0 = [&](int kt) {
        const int o = kt * 128;
#pragma unroll
        for (int i = 0; i < 4; ++i) { Bh0[i] = b_ptr[i][o]; Bl0[i] = b_ptr[i][o + 64]; }
#pragma unroll
        for (int i = 0; i < 4; ++i) { Ah0[i] = a_ptr[i][o]; Al0[i] = a_ptr[i][o + 64]; }
    };
    auto load1 = [&](int kt) {
        const int o = kt * 128;
#pragma unroll
        for (int i = 0; i < 4; ++i) { Bh1[i] = b_ptr[i][o]; Bl1[i] = b_ptr[i][o + 64]; }
#pragma unroll
        for (int i = 0; i < 4; ++i) { Ah1[i] = a_ptr[i][o]; Al1[i] = a_ptr[i][o + 64]; }
    };
    auto comp0 = [&]() {
#pragma unroll
        for (int i = 0; i < 4; ++i)
#pragma unroll
            for (int j = 0; j < 4; ++j) {
                acc[i][j] = MF(Ah0[i], Bh0[j], acc[i][j]);
                acc[i][j] = MF(Ah0[i], Bl0[j], acc[i][j]);
                acc[i][j] = MF(Al0[i], Bh0[j], acc[i][j]);
            }
    };
    auto comp1 = [&]() {
#pragma unroll
        for (int i = 0; i < 4; ++i)
#pragma unroll
            for (int j = 0; j < 4; ++j) {
                acc[i][j] = MF(Ah1[i], Bh1[j], acc[i][j]);
                acc[i][j] = MF(Ah1[i], Bl1[j], acc[i][j]);
                acc[i][j] = MF(Al1[i], Bh1[j], acc[i][j]);
            }
    };

    load0(0);
#pragma unroll 1
    for (int kt = 0; kt < NKT; kt += 2) {       // no barriers in the K-loop
        load1(kt + 1);                          // prefetch while comp0's loads drain
        comp0();
        if (kt + 2 < NKT) load0(kt + 2);
        comp1();
    }

    // Epilogue: score = csq - 2*dot; C/D layout col=lane&15, row=quad*4+reg.
    float csq4[4];
#pragma unroll
    for (int j = 0; j < 4; ++j) csq4[j] = csq[cb + wn * 64 + j * 16 + ln15];

    float bval[16]; int bidx[16];
#pragma unroll
    for (int i = 0; i < 4; ++i)
#pragma unroll
        for (int r = 0; r < 4; ++r) {
            const int rid = i * 4 + r;
            float bv_ = csq4[0] - 2.0f * acc[i][0][r];
            int   bi_ = cb + wn * 64 + ln15;
#pragma unroll
            for (int j = 1; j < 4; ++j) {
                const float s2 = csq4[j] - 2.0f * acc[i][j][r];
                const int   c = cb + wn * 64 + j * 16 + ln15;
                if (s2 < bv_) { bv_ = s2; bi_ = c; }   // ascending c, strict <
            }
            bval[rid] = bv_; bidx[rid] = bi_;
        }
#pragma unroll
    for (int off = 1; off < 16; off <<= 1) {
#pragma unroll
        for (int rid = 0; rid < 16; ++rid) {
            const float ov = __shfl_xor(bval[rid], off, 64);
            const int   oi = __shfl_xor(bidx[rid], off, 64);
            if (ov < bval[rid] || (ov == bval[rid] && oi < bidx[rid])) {
                bval[rid] = ov; bidx[rid] = oi;
            }
        }
    }

    __shared__ float vtab[256];   // [128 rows][2 wn]
    __shared__ int   itab[256];
    if (ln15 == 0) {
#pragma unroll
        for (int i = 0; i < 4; ++i)
#pragma unroll
            for (int r = 0; r < 4; ++r) {
                const int row = wm * 64 + i * 16 + quad * 4 + r;
                vtab[row * 2 + wn] = bval[i * 4 + r];
                itab[row * 2 + wn] = bidx[i * 4 + r];
            }
    }
    __syncthreads();
    if (tid < 128) {
        float v0 = vtab[tid * 2]; int i0 = itab[tid * 2];
        const float v1 = vtab[tid * 2 + 1]; const int i1 = itab[tid * 2 + 1];
        if (v1 < v0 || (v1 == v0 && i1 < i0)) { v0 = v1; i0 = i1; }
        uint2 e; e.x = __float_as_uint(v0); e.y = (unsigned)i0;
        slots[(size_t)(tbase + tid) * 16 + gx] = e;
    }
}

__global__ __launch_bounds__(256)
void slot_reduce_kernel(const uint2* __restrict__ slots, int* __restrict__ out) {
    const int t = blockIdx.x * 256 + threadIdx.x;
    const uint2* s = slots + (size_t)t * 16;
    float bv = __uint_as_float(s[0].x); int bi = (int)s[0].y;
#pragma unroll
    for (int j = 1; j < 16; ++j) {
        const uint2 e = s[j];
        const float v = __uint_as_float(e.x);
        if (v < bv || (v == bv && (int)e.y < bi)) { bv = v; bi = (int)e.y; }
    }
    out[t] = bi;
}

// ---------------- round-3 fallback (proven, used only if ws too small) ------

__global__ __launch_bounds__(256)
void init_ws_kernel(unsigned long long* __restrict__ w) {
    w[blockIdx.x * 256 + threadIdx.x] = 0xFFFFFFFFFFFFFFFFull;
}

__global__ __launch_bounds__(256, 2)
void argmin_mfma_kernel(const float* __restrict__ A, const float* __restrict__ Bc,
                        const float* __restrict__ csq,
                        unsigned long long* __restrict__ ws64) {
    __shared__ unsigned lds[4 * 128 * 20];
    constexpr int AH = 0, AL = 2560, BH = 5120;

    const int tid  = threadIdx.x;
    const int lane = tid & 63;
    const int ln15 = lane & 15;
    const int quad = lane >> 4;
    const int wave = tid >> 6;
    const int wm = wave >> 1, wn = wave & 1;
    const int tbase = blockIdx.x * BM;
    const int cb    = blockIdx.y * BN;

    const int sr  = tid >> 1;
    const int skh = tid & 1;
    const float* gA = A  + (size_t)(tbase + sr) * KK + skh * 16;
    const float* gB = Bc + (size_t)(cb   + sr) * KK + skh * 16;
    const int wword = sr * 20 + skh * 8;

    f32x4 acc[4][4];
#pragma unroll
    for (int i = 0; i < 4; ++i)
#pragma unroll
        for (int j = 0; j < 4; ++j) { f32x4 z = {0.f,0.f,0.f,0.f}; acc[i][j] = z; }

    float4 av[4], bv[4];
#pragma unroll
    for (int p = 0; p < 4; ++p) {
        av[p] = *(const float4*)(gA + p * 4);
        bv[p] = *(const float4*)(gB + p * 4);
    }

    int aw[4], bw[4];
#pragma unroll
    for (int i = 0; i < 4; ++i) {
        aw[i] = AH + (wm * 64 + i * 16 + ln15) * 20 + quad * 4;
        bw[i] = BH + (wn * 64 + i * 16 + ln15) * 20 + quad * 4;
    }

    for (int k0 = 0; k0 < KK; k0 += 32) {
        __syncthreads();
#pragma unroll
        for (int h = 0; h < 2; ++h) {
            float4 v0 = av[2*h], v1 = av[2*h+1];
            f16x2 h00 = __builtin_amdgcn_cvt_pkrtz(v0.x, v0.y);
            f16x2 h01 = __builtin_amdgcn_cvt_pkrtz(v0.z, v0.w);
            f16x2 h10 = __builtin_amdgcn_cvt_pkrtz(v1.x, v1.y);
            f16x2 h11 = __builtin_amdgcn_cvt_pkrtz(v1.z, v1.w);
            f16x2 l00 = __builtin_amdgcn_cvt_pkrtz(v0.x-(float)h00[0], v0.y-(float)h00[1]);
            f16x2 l01 = __builtin_amdgcn_cvt_pkrtz(v0.z-(float)h01[0], v0.w-(float)h01[1]);
            f16x2 l10 = __builtin_amdgcn_cvt_pkrtz(v1.x-(float)h10[0], v1.y-(float)h10[1]);
            f16x2 l11 = __builtin_amdgcn_cvt_pkrtz(v1.z-(float)h11[0], v1.w-(float)h11[1]);
            uint4 hv = {bc(h00), bc(h01), bc(h10), bc(h11)};
            uint4 lv = {bc(l00), bc(l01), bc(l10), bc(l11)};
            *(uint4*)&lds[AH + wword + 4*h] = hv;
            *(uint4*)&lds[AL + wword + 4*h] = lv;

            float4 w0 = bv[2*h], w1 = bv[2*h+1];
            f16x2 g00 = __builtin_amdgcn_cvt_pkrtz(w0.x, w0.y);
            f16x2 g01 = __builtin_amdgcn_cvt_pkrtz(w0.z, w0.w);
            f16x2 g10 = __builtin_amdgcn_cvt_pkrtz(w1.x, w1.y);
            f16x2 g11 = __builtin_amdgcn_cvt_pkrtz(w1.z, w1.w);
            f16x2 m00 = __builtin_amdgcn_cvt_pkrtz(w0.x-(float)g00[0], w0.y-(float)g00[1]);
            f16x2 m01 = __builtin_amdgcn_cvt_pkrtz(w0.z-(float)g01[0], w0.w-(float)g01[1]);
            f16x2 m10 = __builtin_amdgcn_cvt_pkrtz(w1.x-(float)g10[0], w1.y-(float)g10[1]);
            f16x2 m11 = __builtin_amdgcn_cvt_pkrtz(w1.z-(float)g11[0], w1.w-(float)g11[1]);
            uint4 gv = {bc(g00), bc(g01), bc(g10), bc(g11)};
            uint4 mv = {bc(m00), bc(m01), bc(m10), bc(m11)};
            *(uint4*)&lds[BH + wword + 4*h]        = gv;
            *(uint4*)&lds[BH + 2560 + wword + 4*h] = mv;
        }
        __syncthreads();

        const int kn = k0 + 32;
        if (kn < KK) {
#pragma unroll
            for (int p = 0; p < 4; ++p) {
                av[p] = *(const float4*)(gA + kn + p * 4);
                bv[p] = *(const float4*)(gB + kn + p * 4);
            }
        }

        f16x8 a_h[4], a_l[4], b_h[4], b_l[4];
#pragma unroll
        for (int i = 0; i < 4; ++i) {
            a_h[i] = *(const f16x8*)&lds[aw[i]];
            a_l[i] = *(const f16x8*)&lds[aw[i] + 2560];
            b_h[i] = *(const f16x8*)&lds[bw[i]];
            b_l[i] = *(const f16x8*)&lds[bw[i] + 2560];
        }
#pragma unroll
        for (int i = 0; i < 4; ++i)
#pragma unroll
            for (int j = 0; j < 4; ++j) {
                acc[i][j] = __builtin_amdgcn_mfma_f32_16x16x32_f16(a_h[i], b_h[j], acc[i][j], 0, 0, 0);
                acc[i][j] = __builtin_amdgcn_mfma_f32_16x16x32_f16(a_h[i], b_l[j], acc[i][j], 0, 0, 0);
                acc[i][j] = __builtin_amdgcn_mfma_f32_16x16x32_f16(a_l[i], b_h[j], acc[i][j], 0, 0, 0);
            }
    }

    float csq4[4];
#pragma unroll
    for (int j = 0; j < 4; ++j) csq4[j] = csq[cb + wn * 64 + j * 16 + ln15];

    float bval[16]; int bidx[16];
#pragma unroll
    for (int i = 0; i < 4; ++i)
#pragma unroll
        for (int r = 0; r < 4; ++r) {
            const int rid = i * 4 + r;
            float bv_ = csq4[0] - 2.0f * acc[i][0][r];
            int   bi_ = cb + wn * 64 + ln15;
#pragma unroll
            for (int j = 1; j < 4; ++j) {
                const float s = csq4[j] - 2.0f * acc[i][j][r];
                const int   c = cb + wn * 64 + j * 16 + ln15;
                if (s < bv_) { bv_ = s; bi_ = c; }
            }
            bval[rid] = bv_; bidx[rid] = bi_;
        }
#pragma unroll
    for (int off = 1; off < 16; off <<= 1) {
#pragma unroll
        for (int rid = 0; rid < 16; ++rid) {
            const float ov = __shfl_xor(bval[rid], off, 64);
            const int   oi = __shfl_xor(bidx[rid], off, 64);
            if (ov < bval[rid] || (ov == bval[rid] && oi < bidx[rid])) {
                bval[rid] = ov; bidx[rid] = oi;
            }
        }
    }

    __syncthreads();
    float* vtab = (float*)&lds[0];
    int*   itab = (int*)&lds[256];
    if (ln15 == 0) {
#pragma unroll
        for (int i = 0; i < 4; ++i)
#pragma unroll
            for (int r = 0; r < 4; ++r) {
                const int row = wm * 64 + i * 16 + quad * 4 + r;
                vtab[row * 2 + wn] = bval[i * 4 + r];
                itab[row * 2 + wn] = bidx[i * 4 + r];
            }
    }
    __syncthreads();
    if (tid < 128) {
        float v0 = vtab[tid * 2]; int i0 = itab[tid * 2];
        const float v1 = vtab[tid * 2 + 1]; const int i1 = itab[tid * 2 + 1];
        if (v1 < v0 || (v1 == v0 && i1 < i0)) { v0 = v1; i0 = i1; }
        const unsigned b   = __float_as_uint(v0);
        const unsigned key = (b & 0x80000000u) ? ~b : (b | 0x80000000u);
        const unsigned long long pk =
            ((unsigned long long)key << 32) | (unsigned long long)(unsigned)i0;
        atomicMin(&ws64[tbase + tid], pk);
    }
}

__global__ __launch_bounds__(256)
void unpack_kernel(const unsigned long long* __restrict__ w, int* __restrict__ out) {
    const int i = blockIdx.x * 256 + threadIdx.x;
    out[i] = (int)(unsigned)(w[i] & 0xFFFFFFFFull);
}

extern "C" void kernel_launch(void* const* d_in, const int* in_sizes, int n_in,
                              void* d_out, int out_size, void* d_ws, size_t ws_size,
                              hipStream_t stream) {
    const float* embed   = (const float*)d_in[0];   // [32768][768] fp32
    const float* centers = (const float*)d_in[1];   // [2048][768] fp32
    int* out = (int*)d_out;                         // [32768] int32

    if (ws_size >= WS_NEED) {
        uint4* Ap = (uint4*)((char*)d_ws + WS_APACK);
        uint4* Bp = (uint4*)((char*)d_ws + WS_BPACK);
        float* csq   = (float*)((char*)d_ws + WS_CSQ);
        uint2* slots = (uint2*)((char*)d_ws + WS_SLOT);
        fragpack_kernel<<<(NA_UNITS + NB_UNITS) / 4, 256, 0, stream>>>(
            embed, centers, Ap, Bp);
        csq_kernel<<<NN, 64, 0, stream>>>(centers, csq);
        gemm_pack_kernel<<<(MM / BM) * (NN / BN), 256, 0, stream>>>(
            Ap, Bp, csq, slots);
        slot_reduce_kernel<<<MM / 256, 256, 0, stream>>>(slots, out);
    } else {
        unsigned long long* ws64 = (unsigned long long*)d_ws;
        float* csq = (float*)((char*)d_ws + (size_t)MM * 8);
        init_ws_kernel<<<MM / 256, 256, 0, stream>>>(ws64);
        csq_kernel<<<NN, 64, 0, stream>>>(centers, csq);
        argmin_mfma_kernel<<<dim3(MM / BM, NN / BN), 256, 0, stream>>>(
            embed, centers, csq, ws64);
        unpack_kernel<<<MM / 256, 256, 0, stream>>>(ws64, out);
    }
}